// Round 1
// 1118.525 us; speedup vs baseline: 1.7582x; 1.7582x over previous
//
#include <hip/hip_runtime.h>
#include <math.h>

#define CIN 256
#define HIN 38
#define WIN 38
#define NFRAMES 300
#define COUT1 128
#define P1 1521      // 39*39
#define PSTR 1524    // padded spatial stride
#define HW2 1444     // 38*38
#define NSC 5776     // 4*38*38
#define CHUNK 75
#define NCHUNKS 4
#define W1F_LO 131072   // offset (in halves) of lo-part in W1f
#define W2F_LO 16384    // offset (in halves) of lo-part in W2f

typedef _Float16 half8 __attribute__((ext_vector_type(8)));
typedef _Float16 half2v __attribute__((ext_vector_type(2)));
typedef float    f32x4 __attribute__((ext_vector_type(4)));

union H2U { unsigned int u; half2v h; };

// raw barrier: LDS-only drain, never vmcnt — keeps global prefetch in flight
#define LDS_BAR() do { \
    asm volatile("s_waitcnt lgkmcnt(0)" ::: "memory"); \
    __builtin_amdgcn_s_barrier(); \
    asm volatile("" ::: "memory"); \
} while (0)

// ---------------- weight repack: fragment-major packed hi/lo f16 ----------------
__global__ void repack_w1f(const float* __restrict__ W1, _Float16* __restrict__ W1f) {
    int e = blockIdx.x * 256 + threadIdx.x;          // < 131072
    int j  = e & 7;
    int ln = (e >> 3) & 63;
    int mt = (e >> 9) & 7;
    int s  = e >> 12;
    int k  = s * 32 + (ln >> 4) * 8 + j;
    int co = mt * 16 + (ln & 15);
    int kid = k & 3, ci = k >> 2;
    float v = W1[((co * 256) + ci) * 4 + kid] * 64.0f;
    _Float16 h = (_Float16)v;
    W1f[e]          = h;
    W1f[e + W1F_LO] = (_Float16)(v - (float)h);
}

__global__ void repack_w2f(const float* __restrict__ Wc, const float* __restrict__ Wb,
                           _Float16* __restrict__ W2f) {
    int e = blockIdx.x * 256 + threadIdx.x;          // < 16384
    int j  = e & 7;
    int ln = (e >> 3) & 63;
    int mt = (e >> 9) & 1;
    int s  = e >> 10;
    int k  = s * 32 + (ln >> 4) * 8 + j;
    int ch = mt * 16 + (ln & 15);
    int ci = k >> 2, kid = k & 3;
    float v = 0.0f;
    if (ch < 8)       v = Wc[(ch * 128 + ci) * 4 + kid];
    else if (ch < 24) v = Wb[((ch - 8) * 128 + ci) * 4 + kid];
    v *= 64.0f;
    _Float16 h = (_Float16)v;
    W2f[e]          = h;
    W2f[e + W2F_LO] = (_Float16)(v - (float)h);
}

// ---------------- conv1: split-f16 MFMA, dbuf LDS + raw barriers + depth-2 prefetch ----
__global__ __launch_bounds__(256, 2) void conv1_mfma(
    const float* __restrict__ bf, const _Float16* __restrict__ W1f,
    const float* __restrict__ b1, unsigned int* __restrict__ xout, int frame0)
{
    __shared__ __align__(16) _Float16 As[16384];   // buf p at p*8192: hi [0,4096) lo +4096
    __shared__ __align__(16) _Float16 Bs[16384];

    const int tid  = threadIdx.x;
    const int wave = tid >> 6, ln = tid & 63;
    const int wrow = wave >> 1, wcol = wave & 1;
    const int fz = blockIdx.y;
    const int b  = frame0 + fz;
    const int p0 = blockIdx.x * 128;
    const float* bfb = bf + (size_t)b * (CIN * HIN * WIN);

    // B staging geometry: 2 slots/thread; slot = tid + 256r
    int  addr1[2][8];
    bool kok[2][4];
    int  saddr[2];
#pragma unroll
    for (int r = 0; r < 2; ++r) {
        int slot = tid + r * 256;
        int ln_s = slot & 63, nt = slot >> 6;
        int p = p0 + nt * 16 + (ln_s & 15);
        int quad = ln_s >> 4;
        bool pok = p < P1;
        int pp = pok ? p : 0;
        int h = pp / 39, w = pp - h * 39;
#pragma unroll
        for (int kid = 0; kid < 4; ++kid) {
            int hh = h + (kid >> 1) - 1;
            int ww = w + (kid & 1) - 1;
            kok[r][kid] = pok && ((unsigned)hh < 38u) && ((unsigned)ww < 38u);
            int ko = hh * 38 + ww;
#pragma unroll
            for (int t = 0; t < 2; ++t)
                addr1[r][t * 4 + kid] = quad * 2 * 1444 + t * 1444 + ko;
        }
        saddr[r] = slot * 8;
    }

    f32x4 acc[4][4];
#pragma unroll
    for (int i = 0; i < 4; ++i)
#pragma unroll
        for (int j = 0; j < 4; ++j) acc[i][j] = (f32x4)0.0f;

    float bn0[2][8], bn1[2][8];
    half8 an0[4], an1[4];

#define C1_LOAD(SET, S) do { \
        const float* bsrc_ = bfb + (size_t)(S) * 8 * 1444; \
        _Pragma("unroll") \
        for (int r_ = 0; r_ < 2; ++r_) { \
            _Pragma("unroll") \
            for (int j_ = 0; j_ < 8; ++j_) \
                bn##SET[r_][j_] = kok[r_][j_ & 3] ? bsrc_[addr1[r_][j_]] : 0.0f; \
        } \
        const _Float16* wsl_ = W1f + (size_t)(S) * 4096; \
        _Pragma("unroll") \
        for (int f_ = 0; f_ < 4; ++f_) { \
            int o_ = (tid + f_ * 256) * 8; \
            const _Float16* g_ = (f_ < 2) ? (wsl_ + o_) : (wsl_ + W1F_LO + (o_ - 4096)); \
            an##SET[f_] = *(const half8*)g_; \
        } \
    } while (0)

#define C1_STORE(SET, BUF) do { \
        const int bo_ = (BUF) * 8192; \
        _Pragma("unroll") \
        for (int r_ = 0; r_ < 2; ++r_) { \
            half8 hv_, lv_; \
            _Pragma("unroll") \
            for (int j_ = 0; j_ < 8; ++j_) { \
                float v_ = bn##SET[r_][j_] * 32.0f; \
                _Float16 h_ = (_Float16)v_; \
                hv_[j_] = h_; lv_[j_] = (_Float16)(v_ - (float)h_); \
            } \
            *(half8*)&Bs[bo_ + saddr[r_]] = hv_; \
            *(half8*)&Bs[bo_ + 4096 + saddr[r_]] = lv_; \
        } \
        _Pragma("unroll") \
        for (int f_ = 0; f_ < 4; ++f_) \
            *(half8*)&As[bo_ + (tid + f_ * 256) * 8] = an##SET[f_]; \
    } while (0)

#define C1_COMPUTE(BUF) do { \
        const int bo_ = (BUF) * 8192; \
        half8 af_h[4], af_l[4], bf_h[4], bf_l[4]; \
        _Pragma("unroll") \
        for (int t_ = 0; t_ < 4; ++t_) { \
            int mtile_ = wrow * 4 + t_; \
            af_h[t_] = *(const half8*)&As[bo_ + mtile_ * 512 + ln * 8]; \
            af_l[t_] = *(const half8*)&As[bo_ + 4096 + mtile_ * 512 + ln * 8]; \
            int ntile_ = wcol * 4 + t_; \
            bf_h[t_] = *(const half8*)&Bs[bo_ + (ntile_ * 64 + ln) * 8]; \
            bf_l[t_] = *(const half8*)&Bs[bo_ + 4096 + (ntile_ * 64 + ln) * 8]; \
        } \
        __builtin_amdgcn_s_setprio(1); \
        _Pragma("unroll") \
        for (int i_ = 0; i_ < 4; ++i_) { \
            _Pragma("unroll") \
            for (int j_ = 0; j_ < 4; ++j_) \
                acc[i_][j_] = __builtin_amdgcn_mfma_f32_16x16x32_f16(af_h[i_], bf_h[j_], acc[i_][j_], 0, 0, 0); \
        } \
        _Pragma("unroll") \
        for (int i_ = 0; i_ < 4; ++i_) { \
            _Pragma("unroll") \
            for (int j_ = 0; j_ < 4; ++j_) \
                acc[i_][j_] = __builtin_amdgcn_mfma_f32_16x16x32_f16(af_l[i_], bf_h[j_], acc[i_][j_], 0, 0, 0); \
        } \
        _Pragma("unroll") \
        for (int i_ = 0; i_ < 4; ++i_) { \
            _Pragma("unroll") \
            for (int j_ = 0; j_ < 4; ++j_) \
                acc[i_][j_] = __builtin_amdgcn_mfma_f32_16x16x32_f16(af_h[i_], bf_l[j_], acc[i_][j_], 0, 0, 0); \
        } \
        __builtin_amdgcn_s_setprio(0); \
    } while (0)

    // ---- prologue: slices 0 and 1 in flight; slice 0 staged to buf0 ----
    C1_LOAD(0, 0);
    C1_LOAD(1, 1);
    C1_STORE(0, 0);
    LDS_BAR();

    for (int s = 0; s < 32; s += 2) {
        // even slice s: compute buf0; prefetch s+2 into set0; stage set1(s+1)->buf1
        if (s + 2 < 32) C1_LOAD(0, s + 2);
        C1_COMPUTE(0);
        C1_STORE(1, 1);
        LDS_BAR();
        // odd slice s+1: compute buf1; prefetch s+3 into set1; stage set0(s+2)->buf0
        if (s + 3 < 32) C1_LOAD(1, s + 3);
        C1_COMPUTE(1);
        if (s + 2 < 32) {
            C1_STORE(0, 0);
            LDS_BAR();
        }
    }
#undef C1_LOAD
#undef C1_STORE
#undef C1_COMPUTE

    // ---- epilogue: descale, bias, relu, pack {hi,lo} of (x*32) ----
    const float sc = 1.0f / 2048.0f;
    const int rq = ln >> 4, cl = ln & 15;
#pragma unroll
    for (int i = 0; i < 4; ++i) {
#pragma unroll
        for (int j = 0; j < 4; ++j) {
            int p = p0 + (wcol * 4 + j) * 16 + cl;
            if (p < P1) {
#pragma unroll
                for (int rr = 0; rr < 4; ++rr) {
                    int co = (wrow * 4 + i) * 16 + rq * 4 + rr;
                    float t = fmaxf(fmaf(acc[i][j][rr], sc, b1[co]), 0.0f) * 32.0f;
                    H2U u;
                    u.h[0] = (_Float16)t;
                    u.h[1] = (_Float16)(t - (float)u.h[0]);
                    xout[((size_t)fz * COUT1 + co) * PSTR + p] = u.u;
                }
            }
        }
    }
}

// ---------------- stage2: cls+deltas+scores, dbuf LDS + raw barriers + reg A-prefetch ----
__global__ __launch_bounds__(256, 2) void stage2_mfma(
    const unsigned int* __restrict__ xq, const _Float16* __restrict__ W2f,
    const float* __restrict__ bcv, const float* __restrict__ bbv,
    float* __restrict__ scores, float* __restrict__ deltas, int frame0)
{
    __shared__ __align__(16) _Float16 Bs[16384];   // 2 bufs of 8192 halves
    __shared__ float clsb[8][128];

    const int tid  = threadIdx.x;
    const int wave = tid >> 6, ln = tid & 63;
    const int fz = blockIdx.y;
    const int b  = frame0 + fz;
    const int p0 = blockIdx.x * 128;
    const unsigned int* xb = xq + (size_t)fz * COUT1 * PSTR;

    int  addr2[2][8];
    bool sok[2];
    int  saddr[2];
#pragma unroll
    for (int r = 0; r < 2; ++r) {
        int slot = tid + r * 256;
        int ln_s = slot & 63, nt = slot >> 6;
        int p = p0 + nt * 16 + (ln_s & 15);
        int quad = ln_s >> 4;
        sok[r] = p < HW2;
        int pp = sok[r] ? p : 0;
        int h = pp / 38, w = pp - h * 38;
#pragma unroll
        for (int kid = 0; kid < 4; ++kid) {
            int ko = (h + (kid >> 1)) * 39 + (w + (kid & 1));
#pragma unroll
            for (int t = 0; t < 2; ++t)
                addr2[r][t * 4 + kid] = (quad * 2 + t) * PSTR + ko;
        }
        saddr[r] = slot * 8;
    }

    f32x4 acc[2][2];
    acc[0][0] = (f32x4)0.0f; acc[0][1] = (f32x4)0.0f;
    acc[1][0] = (f32x4)0.0f; acc[1][1] = (f32x4)0.0f;

    unsigned int bu0[2][8], bu1[2][8];
    half8 a0_h[2], a0_l[2], a1_h[2], a1_l[2];

#define S2_LOADB(SET, S) do { \
        const unsigned int* row_ = xb + (size_t)(S) * 8 * PSTR; \
        _Pragma("unroll") \
        for (int r_ = 0; r_ < 2; ++r_) { \
            _Pragma("unroll") \
            for (int j_ = 0; j_ < 8; ++j_) \
                bu##SET[r_][j_] = sok[r_] ? row_[addr2[r_][j_]] : 0u; \
        } \
    } while (0)

#define S2_LOADA(SET, S) do { \
        _Pragma("unroll") \
        for (int mt_ = 0; mt_ < 2; ++mt_) { \
            const _Float16* wp_ = W2f + ((size_t)((S) * 2 + mt_) * 64 + ln) * 8; \
            a##SET##_h[mt_] = *(const half8*)wp_; \
            a##SET##_l[mt_] = *(const half8*)(wp_ + W2F_LO); \
        } \
    } while (0)

#define S2_STORE(SET, BUF) do { \
        const int bo_ = (BUF) * 8192; \
        _Pragma("unroll") \
        for (int r_ = 0; r_ < 2; ++r_) { \
            half8 hv_, lv_; \
            _Pragma("unroll") \
            for (int j_ = 0; j_ < 8; ++j_) { \
                H2U t_; t_.u = bu##SET[r_][j_]; \
                hv_[j_] = t_.h[0]; lv_[j_] = t_.h[1]; \
            } \
            *(half8*)&Bs[bo_ + saddr[r_]] = hv_; \
            *(half8*)&Bs[bo_ + 4096 + saddr[r_]] = lv_; \
        } \
    } while (0)

#define S2_COMPUTE(SET, BUF) do { \
        const int bo_ = (BUF) * 8192; \
        half8 b_h[2], b_l[2]; \
        _Pragma("unroll") \
        for (int t_ = 0; t_ < 2; ++t_) { \
            int ntile_ = wave * 2 + t_; \
            b_h[t_] = *(const half8*)&Bs[bo_ + (ntile_ * 64 + ln) * 8]; \
            b_l[t_] = *(const half8*)&Bs[bo_ + 4096 + (ntile_ * 64 + ln) * 8]; \
        } \
        __builtin_amdgcn_s_setprio(1); \
        _Pragma("unroll") \
        for (int i_ = 0; i_ < 2; ++i_) { \
            _Pragma("unroll") \
            for (int j_ = 0; j_ < 2; ++j_) \
                acc[i_][j_] = __builtin_amdgcn_mfma_f32_16x16x32_f16(a##SET##_h[i_], b_h[j_], acc[i_][j_], 0, 0, 0); \
        } \
        _Pragma("unroll") \
        for (int i_ = 0; i_ < 2; ++i_) { \
            _Pragma("unroll") \
            for (int j_ = 0; j_ < 2; ++j_) \
                acc[i_][j_] = __builtin_amdgcn_mfma_f32_16x16x32_f16(a##SET##_l[i_], b_h[j_], acc[i_][j_], 0, 0, 0); \
        } \
        _Pragma("unroll") \
        for (int i_ = 0; i_ < 2; ++i_) { \
            _Pragma("unroll") \
            for (int j_ = 0; j_ < 2; ++j_) \
                acc[i_][j_] = __builtin_amdgcn_mfma_f32_16x16x32_f16(a##SET##_h[i_], b_l[j_], acc[i_][j_], 0, 0, 0); \
        } \
        __builtin_amdgcn_s_setprio(0); \
    } while (0)

    // ---- prologue ----
    S2_LOADB(0, 0);
    S2_LOADA(0, 0);
    S2_LOADB(1, 1);
    S2_LOADA(1, 1);
    S2_STORE(0, 0);
    LDS_BAR();

    for (int s = 0; s < 16; s += 2) {
        // even slice s
        if (s + 2 < 16) S2_LOADB(0, s + 2);
        S2_COMPUTE(0, 0);
        S2_STORE(1, 1);
        if (s + 2 < 16) S2_LOADA(0, s + 2);
        LDS_BAR();
        // odd slice s+1
        if (s + 3 < 16) S2_LOADB(1, s + 3);
        S2_COMPUTE(1, 1);
        if (s + 2 < 16) {
            S2_STORE(0, 0);
            if (s + 3 < 16) S2_LOADA(1, s + 3);
            LDS_BAR();
        }
    }
#undef S2_LOADB
#undef S2_LOADA
#undef S2_STORE
#undef S2_COMPUTE

    // ---- epilogue ----
    const float sc = 1.0f / 2048.0f;
    const int rq = ln >> 4, cl = ln & 15;
#pragma unroll
    for (int mt = 0; mt < 2; ++mt) {
#pragma unroll
        for (int t = 0; t < 2; ++t) {
            int lpx = (wave * 2 + t) * 16 + cl;
            int p = p0 + lpx;
#pragma unroll
            for (int rr = 0; rr < 4; ++rr) {
                int ch = mt * 16 + rq * 4 + rr;
                float v = acc[mt][t][rr] * sc;
                if (ch < 8) {
                    clsb[ch][lpx] = v + bcv[ch];
                } else if (ch < 24 && p < HW2) {
                    deltas[((size_t)b * 16 + (ch - 8)) * HW2 + p] = v + bbv[ch - 8];
                }
            }
        }
    }
    __syncthreads();

    for (int e = tid; e < 512; e += 256) {
        int a = e >> 7, lp = e & 127;
        int p = p0 + lp;
        if (p < HW2) {
            float z1 = clsb[a][lp];
            float z2 = clsb[a + 4][lp];
            float mx = fmaxf(z1, z2);
            float e1 = expf(z1 - mx), e2 = expf(z2 - mx);
            scores[(size_t)b * NSC + a * HW2 + p] = e2 / (e1 + e2);
        }
    }
}

// ---------------- per-frame argmax + box decode ----------------
__global__ __launch_bounds__(256) void argmax_kernel(
    const float* __restrict__ scores, const float* __restrict__ deltas,
    const float* __restrict__ anchors, const float* __restrict__ im_info,
    float* __restrict__ out, float* __restrict__ boxesb, float* __restrict__ ssb)
{
    const int b = blockIdx.x, tid = threadIdx.x;
    const float* s = scores + (size_t)b * NSC;
    float best = -INFINITY;
    int bidx = 0;
    for (int i = tid; i < NSC; i += 256) {
        float v = s[i];
        if (v > best) { best = v; bidx = i; }
    }
    __shared__ float sv[256];
    __shared__ int   si[256];
    sv[tid] = best; si[tid] = bidx;
    __syncthreads();
    for (int stp = 128; stp > 0; stp >>= 1) {
        if (tid < stp) {
            float ov = sv[tid + stp]; int oi = si[tid + stp];
            if (ov > sv[tid] || (ov == sv[tid] && oi < si[tid])) { sv[tid] = ov; si[tid] = oi; }
        }
        __syncthreads();
    }
    if (tid == 0) {
        float ss = sv[0];
        int id = si[0];
        int kprime = id >> 2, aprime = id & 3;
        int hp = kprime / 38, wp = kprime - hp * 38;
        float im = im_info[0];
        float gx = (float)wp * 16.0f, gy = (float)hp * 16.0f;
#pragma unroll
        for (int j = 0; j < 4; ++j) {
            float shift = ((j & 1) == 0) ? gx : gy;
            float prop = anchors[aprime * 4 + j] + shift;
            float dlt = deltas[((size_t)b * 16 + (aprime * 4 + j)) * HW2 + kprime];
            float bx = (prop + dlt) * im;
            out[b * 9 + j]     = truncf(bx / im);
            out[b * 9 + 4 + j] = bx;
            boxesb[b * 4 + j]  = bx;
        }
        out[b * 9 + 8] = ss;
        ssb[b] = ss;
    }
}

// ---------------- proposal loss (nv = 1) ----------------
__global__ void loss_kernel(const int* __restrict__ central_pos,
                            const float* __restrict__ gt,
                            const float* __restrict__ boxesb,
                            const float* __restrict__ ssb,
                            float* __restrict__ out)
{
    if (threadIdx.x != 0 || blockIdx.x != 0) return;
    int idx = central_pos[0];
    bool valid = idx < NFRAMES;
    int idxc = min(max(idx, 0), NFRAMES - 1);
    float vb0 = boxesb[idxc * 4 + 0], vb1 = boxesb[idxc * 4 + 1];
    float vb2 = boxesb[idxc * 4 + 2], vb3 = boxesb[idxc * 4 + 3];
    float vs = ssb[idxc];
    float g0 = gt[0], g1 = gt[1], g2 = gt[2], g3 = gt[3];
    float xi1 = fmaxf(g0, vb0), yi1 = fmaxf(g1, vb1);
    float xi2 = fmaxf(g2, vb2), yi2 = fmaxf(g3, vb3);
    float inter = (xi2 - xi1) * (yi2 - yi1);
    float a1 = (g2 - g0) * (g3 - g1);
    float a2 = (vb2 - vb0) * (vb3 - vb1);
    float iou = inter / (a1 + a2 - inter);
    float lv = (iou > 0.7f) ? -logf(vs + 1e-5f) : -logf(1.0f - vs + 1e-5f);
    out[NFRAMES * 9] = valid ? lv : 0.0f;
}

// ---------------- host launcher ----------------
extern "C" void kernel_launch(void* const* d_in, const int* in_sizes, int n_in,
                              void* d_out, int out_size, void* d_ws, size_t ws_size,
                              hipStream_t stream) {
    const float* base_feat   = (const float*)d_in[0];
    const int*   central_pos = (const int*)d_in[1];
    const float* im_info     = (const float*)d_in[2];
    const float* gt_boxes    = (const float*)d_in[3];
    const float* W1 = (const float*)d_in[4];
    const float* b1 = (const float*)d_in[5];
    const float* Wc = (const float*)d_in[6];
    const float* bc = (const float*)d_in[7];
    const float* Wb = (const float*)d_in[8];
    const float* bb = (const float*)d_in[9];
    const float* anchors = (const float*)d_in[10];
    float* out = (float*)d_out;

    float* p = (float*)d_ws;
    unsigned int* xbuf = (unsigned int*)p; p += (size_t)CHUNK * COUT1 * PSTR;
    float* scores = p;  p += (size_t)NFRAMES * NSC;
    float* deltas = p;  p += (size_t)NFRAMES * 16 * HW2;
    _Float16* w1f = (_Float16*)p; p += 131072;   // 262144 halves
    _Float16* w2f = (_Float16*)p; p += 16384;    // 32768 halves
    float* boxesb = p;  p += NFRAMES * 4;
    float* ssb    = p;

    repack_w1f<<<512, 256, 0, stream>>>(W1, w1f);
    repack_w2f<<<64, 256, 0, stream>>>(Wc, Wb, w2f);

    for (int c = 0; c < NCHUNKS; ++c) {
        int f0 = c * CHUNK;
        conv1_mfma<<<dim3(12, CHUNK), 256, 0, stream>>>(base_feat, w1f, b1, xbuf, f0);
        stage2_mfma<<<dim3(12, CHUNK), 256, 0, stream>>>(xbuf, w2f, bc, bb, scores, deltas, f0);
    }
    argmax_kernel<<<NFRAMES, 256, 0, stream>>>(scores, deltas, anchors, im_info, out, boxesb, ssb);
    loss_kernel<<<1, 64, 0, stream>>>(central_pos, gt_boxes, boxesb, ssb, out);
}